// Round 5
// baseline (202.667 us; speedup 1.0000x reference)
//
#include <hip/hip_runtime.h>
#include <stdint.h>

typedef __attribute__((ext_vector_type(4))) float floatx4;
typedef __attribute__((ext_vector_type(8))) __bf16 bf16x8;

#define K_DIM 2048
#define NH 96
#define M_ROWS 16384
#define BK 32
#define KSLICE (K_DIM / 4)            // 512 per wave (4 waves cover full K)
#define STEPS (KSLICE / BK)           // 16
#define NSLAB (K_DIM / BK)            // 64
#define WSLAB 6144                    // 6 frags * 1 KB, tight
#define RS 100                        // padded row stride (floats) for epilogue reduce
#define MTILE 16                      // M rows per block (high-occupancy variant)
#define XBUF 4                        // x LDS buffers, 2 KB each per wave

// async global->LDS, 16B/lane; LDS dest = wave-uniform base (+ lane*16 implicit)
#define GLD16(gp, lp) __builtin_amdgcn_global_load_lds( \
    (const __attribute__((address_space(1))) uint32_t*)(gp), \
    (__attribute__((address_space(3))) uint32_t*)(lp), 16, 0, 0)

// s_waitcnt imm: vmcnt[3:0]+[15:14] (6 bits), expcnt[6:4], lgkmcnt[11:8].
// WAIT_VM: vmcnt<=n, lgkm/exp unconstrained. Memory clobbers pin load-issue order.
#define WAIT_VM(n) do { asm volatile("" ::: "memory"); \
    __builtin_amdgcn_s_waitcnt((((n) & 15) | (((n) >> 4) << 14)) | (15 << 8) | (7 << 4)); \
    asm volatile("" ::: "memory"); } while (0)
// lgkmcnt(0) only; vmcnt unconstrained. Guards LDS WAR before re-staging.
#define WAIT_LGKM0() do { asm volatile("" ::: "memory"); \
    __builtin_amdgcn_s_waitcnt((3u << 14) | (0 << 8) | (7 << 4) | 15); \
    asm volatile("" ::: "memory"); } while (0)

// --- Kernel 1: pack W into bf16 B-frags, BK=32 slabs (one-time cvt, lane-ordered
// so the GEMM's B-frag load is a single coalesced dwordx4 from L2).
// Frag (s,t), lane l, elem j = W[t*16+(l&15)][s*32+(l>>4)*8+j]   (layout verified)
__global__ __launch_bounds__(256) void wpack_kernel(const float* __restrict__ W,
                                                    uint8_t* __restrict__ WbF) {
    int u = blockIdx.x * 256 + threadIdx.x;   // 0..24575 = 64 slabs * 6 frags * 64 lanes
    int l  = u & 63;
    int fr = u >> 6;
    int t  = fr % 6;
    int s  = fr / 6;
    int head = t * 16 + (l & 15);
    int k    = s * 32 + (l >> 4) * 8;
    const float* wp = W + (size_t)head * K_DIM + k;
    float4 v0 = *(const float4*)wp;
    float4 v1 = *(const float4*)(wp + 4);
    bf16x8 o;
    o[0] = (__bf16)v0.x; o[1] = (__bf16)v0.y; o[2] = (__bf16)v0.z; o[3] = (__bf16)v0.w;
    o[4] = (__bf16)v1.x; o[5] = (__bf16)v1.y; o[6] = (__bf16)v1.z; o[7] = (__bf16)v1.w;
    *(bf16x8*)(WbF + (size_t)s * WSLAB + t * 1024 + l * 16) = o;
}

// --- Kernel 2: high-occupancy GEMM. M-tile 16 rows, grid 1024 -> 4 blocks/CU
// (16 waves/CU, 2x the TLP of the M=32 variant at identical in-flight bytes).
// x via GLD16 into 4 per-wave LDS buffers (3 slabs in flight); W bf16 frags in
// registers 2-deep (L2-resident). Barrier-free K-loop, counted-vmcnt paced.
// <=128 VGPR (launch_bounds 256,4), 32 KB LDS.
__global__ __launch_bounds__(256, 4) void mh_gemm_kernel(const float* __restrict__ x,
                                                         const uint8_t* __restrict__ WbF,
                                                         const float* __restrict__ bias,
                                                         float* __restrict__ out) {
    // staging view: [buf 0..3][wave 0..3][2048 B] = 32 KB
    // reduce view:  4 waves * 16 rows * RS floats = 25600 B (overlay, post-loop)
    __shared__ __align__(16) uint8_t smem[XBUF * 4 * 2048];

    const int tid  = threadIdx.x;
    const int w    = tid >> 6;
    const int lane = tid & 63;
    const int n15  = lane & 15;
    const int quad = lane >> 4;
    const int m0   = (int)blockIdx.x * MTILE;

    // x staging: lane -> (row = lane>>3, chunk = lane&7); global chunk = (lane&7)^(row&7)
    // so LDS slot c of row r holds global chunk c^(r&7). Coalesced 128B/row.
    const float* xg0 = x + (size_t)(m0 + (lane >> 3)) * K_DIM
                         + (size_t)w * KSLICE
                         + (((lane & 7) ^ ((lane >> 3) & 7)) << 2);
    // B-frag: slab S = w*16 + s, frag t; 64 lanes * 16 B contiguous.
    const uint8_t* wg0 = WbF + (size_t)(w * STEPS) * WSLAB + lane * 16;

    auto stage_x = [&](int s) {   // 2 vm-ops, rows 0-7 and 8-15 of the tile
        uint8_t* xb = smem + (size_t)(((s & 3) * 4 + w)) * 2048;
        const float* xg = xg0 + s * BK;
        GLD16(xg,             xb);
        GLD16(xg + 8 * K_DIM, xb + 1024);
    };

    uint4 wf[2][6];               // 48 VGPR, 2 slabs deep
    auto loadW = [&](int s) {     // 6 vm-ops
        const uint8_t* p = wg0 + (size_t)s * WSLAB;
        uint4* d = wf[s & 1];
#pragma unroll
        for (int t = 0; t < 6; ++t)
            d[t] = *(const uint4*)(p + t * 1024);
    };

    floatx4 acc[6] = {};

    auto compute = [&](int s) {
        const float* xsw = (const float*)(smem + (size_t)(((s & 3) * 4 + w)) * 2048);
        const float* rowp = xsw + n15 * 32;
        const int sw = n15 & 7;
        float4 lo = *(const float4*)(rowp + (((quad * 2    ) ^ sw) << 2));
        float4 hi = *(const float4*)(rowp + (((quad * 2 + 1) ^ sw) << 2));
        bf16x8 a;
        a[0] = (__bf16)lo.x; a[1] = (__bf16)lo.y;
        a[2] = (__bf16)lo.z; a[3] = (__bf16)lo.w;
        a[4] = (__bf16)hi.x; a[5] = (__bf16)hi.y;
        a[6] = (__bf16)hi.z; a[7] = (__bf16)hi.w;
        const uint4* ws = wf[s & 1];
#pragma unroll
        for (int t = 0; t < 6; ++t) {
            bf16x8 bb = __builtin_bit_cast(bf16x8, ws[t]);
            acc[t] = __builtin_amdgcn_mfma_f32_16x16x32_bf16(a, bb, acc[t], 0, 0, 0);
        }
    };

    // Prologue issue order: X0 X1 W0 X2 W1 X3 = 20 vm-ops outstanding.
    // Invariant at iter-s wait: leaving 10 newest forces {X(s..s+1), W(s)} done.
    stage_x(0); stage_x(1); loadW(0); stage_x(2); loadW(1); stage_x(3);
#pragma unroll
    for (int s = 0; s < STEPS; ++s) {
        if      (s <= STEPS - 4) WAIT_VM(10);
        else if (s == STEPS - 3) WAIT_VM(8);
        else if (s == STEPS - 2) WAIT_VM(6);
        else                     WAIT_VM(0);
        compute(s);
        if (s + 2 < STEPS) loadW(s + 2);        // into wf[s&1], freed by compute(s)
        if (s + 4 < STEPS) {
            WAIT_LGKM0();                       // ds_reads of buf s&3 drained
            stage_x(s + 4);                     // overwrite buf s&3
        }
    }

    // --- epilogue: cross-wave K reduction in LDS, + bias, direct out write ---
    __syncthreads();               // all waves done staging/reading; repurpose LDS
    float* red = (float*)smem;     // [wave][16 rows][RS floats] = 25600 B
    {
        float* rw = red + w * (MTILE * RS);
#pragma unroll
        for (int t = 0; t < 6; ++t)
#pragma unroll
            for (int r = 0; r < 4; ++r)
                // C/D: col=n15, row=quad*4+r [m89-verified]
                rw[(quad * 4 + r) * RS + t * 16 + n15] = acc[t][r];
    }
    __syncthreads();
#pragma unroll
    for (int k = 0; k < 2; ++k) {
        int e4 = k * 256 + tid;            // 384 float4 outputs (16*96/4)
        if (e4 < (MTILE * NH / 4)) {
            int e    = e4 * 4;
            int row  = e / NH;
            int head = e % NH;             // multiple of 4
            const float* r0 = red + row * RS + head;
            float4 s0 = *(const float4*)(r0);
            float4 s1 = *(const float4*)(r0 + 1 * MTILE * RS);
            float4 s2 = *(const float4*)(r0 + 2 * MTILE * RS);
            float4 s3 = *(const float4*)(r0 + 3 * MTILE * RS);
            float4 bv = *(const float4*)(bias + head);
            float4 o;
            o.x = s0.x + s1.x + s2.x + s3.x + bv.x;
            o.y = s0.y + s1.y + s2.y + s3.y + bv.y;
            o.z = s0.z + s1.z + s2.z + s3.z + bv.z;
            o.w = s0.w + s1.w + s2.w + s3.w + bv.w;
            *(float4*)(out + (size_t)(m0 + row) * NH + head) = o;
        }
    }
}

extern "C" void kernel_launch(void* const* d_in, const int* in_sizes, int n_in,
                              void* d_out, int out_size, void* d_ws, size_t ws_size,
                              hipStream_t stream) {
    const float* x = (const float*)d_in[0];
    const float* W = (const float*)d_in[1];
    const float* b = (const float*)d_in[2];
    float* out = (float*)d_out;

    // Workspace poison fills are unconditional (proven round 2) -> using it is free.
    uint8_t* WbF = (uint8_t*)d_ws;   // 384 KB packed bf16 W

    wpack_kernel<<<96, 256, 0, stream>>>(W, WbF);
    mh_gemm_kernel<<<M_ROWS / MTILE, 256, 0, stream>>>(x, WbF, b, out);
}

// Round 6
// 196.660 us; speedup vs baseline: 1.0305x; 1.0305x over previous
//
#include <hip/hip_runtime.h>
#include <stdint.h>

typedef __attribute__((ext_vector_type(4))) float floatx4;
typedef __attribute__((ext_vector_type(8))) __bf16 bf16x8;

#define K_DIM 2048
#define NH 96
#define M_ROWS 16384
#define BK 32
#define KSLICE (K_DIM / 4)            // 512 per wave (4 waves cover full K)
#define STEPS (KSLICE / BK)           // 16
#define NSLAB (K_DIM / BK)            // 64
#define WSLAB 6144                    // 6 frags * 1 KB, tight
#define RS 100                        // padded row stride (floats) for epilogue reduce
#define XBUF 4                        // x LDS buffers (quad-buffer, 3 slabs in flight)

// async global->LDS, 16B/lane; LDS dest = wave-uniform base (+ lane*16 implicit)
#define GLD16(gp, lp) __builtin_amdgcn_global_load_lds( \
    (const __attribute__((address_space(1))) uint32_t*)(gp), \
    (__attribute__((address_space(3))) uint32_t*)(lp), 16, 0, 0)

// s_waitcnt imm: vmcnt[3:0]+[15:14] (6 bits), expcnt[6:4], lgkmcnt[11:8].
// WAIT_VM: vmcnt<=n, lgkm/exp unconstrained. Memory clobbers pin load-issue order.
#define WAIT_VM(n) do { asm volatile("" ::: "memory"); \
    __builtin_amdgcn_s_waitcnt((((n) & 15) | (((n) >> 4) << 14)) | (15 << 8) | (7 << 4)); \
    asm volatile("" ::: "memory"); } while (0)
// lgkmcnt(0) only; vmcnt unconstrained. Guards LDS WAR before re-staging.
#define WAIT_LGKM0() do { asm volatile("" ::: "memory"); \
    __builtin_amdgcn_s_waitcnt((3u << 14) | (0 << 8) | (7 << 4) | 15); \
    asm volatile("" ::: "memory"); } while (0)

// --- Kernel 1: pack W into bf16 B-frags, BK=32 slabs (one-time cvt, lane-ordered
// so the GEMM's B-frag load is a single coalesced dwordx4 from L2).
// Frag (s,t), lane l, elem j = W[t*16+(l&15)][s*32+(l>>4)*8+j]   (layout verified)
__global__ __launch_bounds__(256) void wpack_kernel(const float* __restrict__ W,
                                                    uint8_t* __restrict__ WbF) {
    int u = blockIdx.x * 256 + threadIdx.x;   // 0..24575 = 64 slabs * 6 frags * 64 lanes
    int l  = u & 63;
    int fr = u >> 6;
    int t  = fr % 6;
    int s  = fr / 6;
    int head = t * 16 + (l & 15);
    int k    = s * 32 + (l >> 4) * 8;
    const float* wp = W + (size_t)head * K_DIM + k;
    float4 v0 = *(const float4*)wp;
    float4 v1 = *(const float4*)(wp + 4);
    bf16x8 o;
    o[0] = (__bf16)v0.x; o[1] = (__bf16)v0.y; o[2] = (__bf16)v0.z; o[3] = (__bf16)v0.w;
    o[4] = (__bf16)v1.x; o[5] = (__bf16)v1.y; o[6] = (__bf16)v1.z; o[7] = (__bf16)v1.w;
    *(bf16x8*)(WbF + (size_t)s * WSLAB + t * 1024 + l * 16) = o;
}

// --- Kernel 2: deep-pipeline GEMM (best measured variant, round 4: 197.2 us).
// x via GLD16 into 4 LDS buffers (3 slabs in flight, zero VGPR cost); W bf16
// frags in registers 3-deep (L2-resident). Issue-order invariant: W(k) issued
// before X(k+1), so counted vmcnt(24) forces exactly {X(s), W(s)} and leaves
// 24 ops (3 x-slabs + 3 W-slabs) in flight. Barrier-free K-loop (per-wave LDS
// regions). ~160 VGPR, 64 KB LDS, 2 blocks/CU.
__global__ __launch_bounds__(256, 2) void mh_gemm_kernel(const float* __restrict__ x,
                                                         const uint8_t* __restrict__ WbF,
                                                         const float* __restrict__ bias,
                                                         float* __restrict__ out) {
    // staging view: [buf 0..3][wave 0..3][4096 B] = 64 KB
    // reduce view:  4 waves * 32 rows * RS floats = 51200 B (overlay, post-loop)
    __shared__ __align__(16) uint8_t smem[XBUF * 4 * 4096];

    const int tid  = threadIdx.x;
    const int w    = tid >> 6;
    const int lane = tid & 63;
    const int n15  = lane & 15;
    const int quad = lane >> 4;
    const int m0   = (int)blockIdx.x * 32;

    // x staging: lane -> (row = lane>>3, chunk = lane&7); global chunk = (lane&7)^(row&7)
    // so LDS slot c of row r holds global chunk c^(r&7). Coalesced 128B/row.
    const float* xg0 = x + (size_t)(m0 + (lane >> 3)) * K_DIM
                         + (size_t)w * KSLICE
                         + (((lane & 7) ^ ((lane >> 3) & 7)) << 2);
    // B-frag: slab S = w*16 + s, frag t; 64 lanes * 16 B contiguous.
    const uint8_t* wg0 = WbF + (size_t)(w * STEPS) * WSLAB + lane * 16;

    auto stage_x = [&](int s) {   // 4 vm-ops
        uint8_t* xb = smem + (size_t)(((s % XBUF) * 4 + w)) * 4096;
        const float* xg = xg0 + s * BK;
        GLD16(xg,              xb + 0 * 1024);
        GLD16(xg +  8 * K_DIM, xb + 1 * 1024);
        GLD16(xg + 16 * K_DIM, xb + 2 * 1024);
        GLD16(xg + 24 * K_DIM, xb + 3 * 1024);
    };

    uint4 wf[3][6];               // 72 VGPR, 3 slabs deep
    auto loadW = [&](int s) {     // 6 vm-ops
        const uint8_t* p = wg0 + (size_t)s * WSLAB;
        uint4* d = wf[s % 3];
#pragma unroll
        for (int t = 0; t < 6; ++t)
            d[t] = *(const uint4*)(p + t * 1024);
    };

    floatx4 acc[2][6] = {};

    auto compute = [&](int s) {
        const float* xsw = (const float*)(smem + (size_t)(((s % XBUF) * 4 + w)) * 4096);
        bf16x8 af[2];
#pragma unroll
        for (int h = 0; h < 2; ++h) {
            const int R = h * 16 + n15;
            const float* rowp = xsw + R * 32;
            const int sw = n15 & 7;
            float4 lo = *(const float4*)(rowp + (((quad * 2    ) ^ sw) << 2));
            float4 hi = *(const float4*)(rowp + (((quad * 2 + 1) ^ sw) << 2));
            bf16x8 a;
            a[0] = (__bf16)lo.x; a[1] = (__bf16)lo.y;
            a[2] = (__bf16)lo.z; a[3] = (__bf16)lo.w;
            a[4] = (__bf16)hi.x; a[5] = (__bf16)hi.y;
            a[6] = (__bf16)hi.z; a[7] = (__bf16)hi.w;
            af[h] = a;
        }
        const uint4* ws = wf[s % 3];
#pragma unroll
        for (int t = 0; t < 6; ++t) {
            bf16x8 bb = __builtin_bit_cast(bf16x8, ws[t]);
            acc[0][t] = __builtin_amdgcn_mfma_f32_16x16x32_bf16(af[0], bb, acc[0][t], 0, 0, 0);
            acc[1][t] = __builtin_amdgcn_mfma_f32_16x16x32_bf16(af[1], bb, acc[1][t], 0, 0, 0);
        }
    };

    // Prologue issue order: X0 W0 X1 W1 X2 W2 X3 = 34 vm-ops outstanding.
    stage_x(0); loadW(0); stage_x(1); loadW(1); stage_x(2); loadW(2); stage_x(3);
#pragma unroll
    for (int s = 0; s < STEPS; ++s) {
        // Force {X(s), W(s)} (oldest 10); keep the rest in flight.
        if      (s <= STEPS - 4) WAIT_VM(24);   // X(s+1..s+3), W(s+1..s+2) stay
        else if (s == STEPS - 3) WAIT_VM(20);   // X14,15 + W14,15
        else if (s == STEPS - 2) WAIT_VM(10);   // X15 + W15
        else                     WAIT_VM(0);
        compute(s);
        if (s + 3 < STEPS) loadW(s + 3);        // into wf[s%3], freed by compute(s)
        if (s + 4 < STEPS) {
            WAIT_LGKM0();                       // ds_reads of buf s%4 drained
            stage_x(s + 4);                     // overwrite buf s%4
        }
    }

    // --- epilogue: cross-wave K reduction in LDS, + bias, direct out write ---
    __syncthreads();               // all waves done staging/reading; repurpose LDS
    float* red = (float*)smem;     // 4 waves * 32 rows * RS floats = 51200 B
    {
        float* rw = red + w * (32 * RS);
#pragma unroll
        for (int h = 0; h < 2; ++h)
#pragma unroll
            for (int t = 0; t < 6; ++t)
#pragma unroll
                for (int r = 0; r < 4; ++r)
                    // C/D: col=n15, row=quad*4+r [m89-verified]
                    rw[(h * 16 + quad * 4 + r) * RS + t * 16 + n15] = acc[h][t][r];
    }
    __syncthreads();
#pragma unroll
    for (int k = 0; k < 3; ++k) {
        int e4   = k * 256 + tid;          // 768 float4 outputs (32*96/4)
        int e    = e4 * 4;
        int row  = e / NH;
        int head = e % NH;                 // multiple of 4
        const float* r0 = red + row * RS + head;
        float4 s0 = *(const float4*)(r0);
        float4 s1 = *(const float4*)(r0 + 1 * 32 * RS);
        float4 s2 = *(const float4*)(r0 + 2 * 32 * RS);
        float4 s3 = *(const float4*)(r0 + 3 * 32 * RS);
        float4 bv = *(const float4*)(bias + head);
        float4 o;
        o.x = s0.x + s1.x + s2.x + s3.x + bv.x;
        o.y = s0.y + s1.y + s2.y + s3.y + bv.y;
        o.z = s0.z + s1.z + s2.z + s3.z + bv.z;
        o.w = s0.w + s1.w + s2.w + s3.w + bv.w;
        *(float4*)(out + (size_t)(m0 + row) * NH + head) = o;
    }
}

extern "C" void kernel_launch(void* const* d_in, const int* in_sizes, int n_in,
                              void* d_out, int out_size, void* d_ws, size_t ws_size,
                              hipStream_t stream) {
    const float* x = (const float*)d_in[0];
    const float* W = (const float*)d_in[1];
    const float* b = (const float*)d_in[2];
    float* out = (float*)d_out;

    // Workspace poison fills are unconditional (proven round 2) -> using it is free.
    uint8_t* WbF = (uint8_t*)d_ws;   // 384 KB packed bf16 W

    wpack_kernel<<<96, 256, 0, stream>>>(W, WbF);
    mh_gemm_kernel<<<M_ROWS / 32, 256, 0, stream>>>(x, WbF, b, out);
}